// Round 2
// baseline (742.351 us; speedup 1.0000x reference)
//
#include <hip/hip_runtime.h>
#include <hip/hip_bf16.h>

// Problem constants (fixed by the reference)
#define Hd   1024
#define Bd   32
#define Nd   20
#define Kd   10
#define NKd  200   // N*K support rows per batch
#define NKP  208   // padded to 13 * 16
#define Qd   2048
#define BM   64    // query rows per block
#define BK   32    // K-slab per MFMA step
#define LDA  40    // LDS row stride in bf16 units (BK + 8 pad)
#define EPSf 1e-5f
#define TAU  0.02f // top-2 gap below which we refine in fp64
#define MAXF 8192

typedef __attribute__((ext_vector_type(8))) short bf16x8;
typedef __attribute__((ext_vector_type(4))) float f32x4;

static __device__ __forceinline__ unsigned short f2bf(float f) {
  union { float f; unsigned u; } c; c.f = f;
  unsigned r = c.u + 0x7FFFu + ((c.u >> 16) & 1u);  // RNE
  return (unsigned short)(r >> 16);
}
static __device__ __forceinline__ float bf2f(unsigned short h) {
  union { unsigned u; float f; } c; c.u = ((unsigned)h) << 16;
  return c.f;
}

// ---------------- LayerNorm support -> split bf16 (hi, lo), one wave per row ----------------
__global__ __launch_bounds__(256) void ln_support(const float* __restrict__ x,
                                                  const float* __restrict__ gamma,
                                                  const float* __restrict__ beta,
                                                  unsigned short* __restrict__ y_hi,
                                                  unsigned short* __restrict__ y_lo,
                                                  int rows) {
  int wave = threadIdx.x >> 6, lane = threadIdx.x & 63;
  int row = blockIdx.x * 4 + wave;
  if (row >= rows) return;
  const float4* xr = (const float4*)(x + (size_t)row * Hd);
  float4 v[4];
  float s = 0.f, ss = 0.f;
#pragma unroll
  for (int j = 0; j < 4; ++j) {
    v[j] = xr[lane + j * 64];
    s  += v[j].x + v[j].y + v[j].z + v[j].w;
    ss += v[j].x * v[j].x + v[j].y * v[j].y + v[j].z * v[j].z + v[j].w * v[j].w;
  }
#pragma unroll
  for (int o = 32; o; o >>= 1) { s += __shfl_xor(s, o, 64); ss += __shfl_xor(ss, o, 64); }
  float mean = s * (1.0f / Hd);
  float rstd = rsqrtf(ss * (1.0f / Hd) - mean * mean + EPSf);
  const float4* gr = (const float4*)gamma;
  const float4* br = (const float4*)beta;
  ushort4* yh = (ushort4*)(y_hi + (size_t)row * Hd);
  ushort4* yl = (ushort4*)(y_lo + (size_t)row * Hd);
#pragma unroll
  for (int j = 0; j < 4; ++j) {
    float4 g = gr[lane + j * 64], bb = br[lane + j * 64];
    float nx[4] = {(v[j].x - mean) * rstd * g.x + bb.x,
                   (v[j].y - mean) * rstd * g.y + bb.y,
                   (v[j].z - mean) * rstd * g.z + bb.z,
                   (v[j].w - mean) * rstd * g.w + bb.w};
    ushort4 ph, pl;
    ph.x = f2bf(nx[0]); pl.x = f2bf(nx[0] - bf2f(ph.x));
    ph.y = f2bf(nx[1]); pl.y = f2bf(nx[1] - bf2f(ph.y));
    ph.z = f2bf(nx[2]); pl.z = f2bf(nx[2] - bf2f(ph.z));
    ph.w = f2bf(nx[3]); pl.w = f2bf(nx[3] - bf2f(ph.w));
    yh[lane + j * 64] = ph;
    yl[lane + j * 64] = pl;
  }
}

// ---------------- query row stats (mean, rstd), one wave per row ----------------
__global__ __launch_bounds__(256) void row_stats(const float* __restrict__ x,
                                                 float2* __restrict__ st, int rows) {
  int wave = threadIdx.x >> 6, lane = threadIdx.x & 63;
  int row = blockIdx.x * 4 + wave;
  if (row >= rows) return;
  const float4* xr = (const float4*)(x + (size_t)row * Hd);
  float s = 0.f, ss = 0.f;
#pragma unroll
  for (int j = 0; j < 4; ++j) {
    float4 v = xr[lane + j * 64];
    s  += v.x + v.y + v.z + v.w;
    ss += v.x * v.x + v.y * v.y + v.z * v.z + v.w * v.w;
  }
#pragma unroll
  for (int o = 32; o; o >>= 1) { s += __shfl_xor(s, o, 64); ss += __shfl_xor(ss, o, 64); }
  float mean = s * (1.0f / Hd);
  float rstd = rsqrtf(ss * (1.0f / Hd) - mean * mean + EPSf);
  if (lane == 0) st[row] = make_float2(mean, rstd);
}

// ---------------- fused split-bf16 GEMM + group-max/min/argmax + tie flagging ----------------
// grid: (Qd/BM, Bd), block: 256 (4 waves). Wave w owns query rows [w*16, w*16+16).
__global__ __launch_bounds__(256) void gemm_reduce(
    const float* __restrict__ query, const float2* __restrict__ qstats,
    const unsigned short* __restrict__ s_hi, const unsigned short* __restrict__ s_lo,
    const float* __restrict__ gamma, const float* __restrict__ beta,
    float* __restrict__ out_logits, float* __restrict__ out_pred,
    int* __restrict__ flag_cnt, int* __restrict__ flag_list) {
  __shared__ union {
    struct {
      unsigned short Ah[BM][LDA], Al[BM][LDA];      // 2 * 5.12 KB
      unsigned short Bh[NKP][LDA], Bl[NKP][LDA];    // 2 * 16.64 KB
    } st;                                           // 43.5 KB
    struct { float z[BM][NKP]; float gmax[BM][Nd]; } rd;  // 58.4 KB
  } sm;

  int b = blockIdx.y;
  int m0 = blockIdx.x * BM;
  int t = threadIdx.x;
  int wave = t >> 6, lane = t & 63;
  int m = lane & 15, quad = lane >> 4;

  const size_t qrow0 = (size_t)b * Qd + m0;
  int a_row = t >> 2, a_k = (t & 3) * 8;
  float2 stt = qstats[qrow0 + a_row];
  float mean = stt.x, rstd = stt.y;
  const float* qptr = query + (qrow0 + a_row) * Hd;
  const unsigned short* sbh = s_hi + (size_t)b * NKd * Hd;
  const unsigned short* sbl = s_lo + (size_t)b * NKd * Hd;

  f32x4 acc[13];
#pragma unroll
  for (int i = 0; i < 13; ++i) acc[i] = (f32x4){0.f, 0.f, 0.f, 0.f};

  for (int kk = 0; kk < Hd; kk += BK) {
    // ---- global loads into registers ----
    const float4* qp = (const float4*)(qptr + kk + a_k);
    float4 x0 = qp[0], x1 = qp[1];
    const float4* gp = (const float4*)(gamma + kk + a_k);
    const float4* bp = (const float4*)(beta + kk + a_k);
    float4 g0 = gp[0], g1 = gp[1], e0 = bp[0], e1 = bp[1];
    float xs[8] = {x0.x, x0.y, x0.z, x0.w, x1.x, x1.y, x1.z, x1.w};
    float gs[8] = {g0.x, g0.y, g0.z, g0.w, g1.x, g1.y, g1.z, g1.w};
    float es[8] = {e0.x, e0.y, e0.z, e0.w, e1.x, e1.y, e1.z, e1.w};
    bf16x8 avh, avl;
#pragma unroll
    for (int j = 0; j < 8; ++j) {
      float nx = (xs[j] - mean) * rstd * gs[j] + es[j];
      unsigned short h = f2bf(nx);
      avh[j] = (short)h;
      avl[j] = (short)f2bf(nx - bf2f(h));
    }

    // B: 208 rows * 4 vecs = 832 bf16x8 vectors per plane; rows >= 200 are zero
    bf16x8 bvh[4], bvl[4];
#pragma unroll
    for (int i = 0; i < 4; ++i) {
      int idx = t + i * 256;
      int brow = idx >> 2, bk = (idx & 3) * 8;
      if (idx < 832 && brow < NKd) {
        size_t off = (size_t)brow * Hd + kk + bk;
        bvh[i] = *(const bf16x8*)(sbh + off);
        bvl[i] = *(const bf16x8*)(sbl + off);
      } else {
#pragma unroll
        for (int j = 0; j < 8; ++j) { bvh[i][j] = 0; bvl[i][j] = 0; }
      }
    }

    __syncthreads();  // previous tile fully consumed
    *(bf16x8*)&sm.st.Ah[a_row][a_k] = avh;
    *(bf16x8*)&sm.st.Al[a_row][a_k] = avl;
#pragma unroll
    for (int i = 0; i < 4; ++i) {
      int idx = t + i * 256;
      if (idx < 832) {
        int brow = idx >> 2, bk = (idx & 3) * 8;
        *(bf16x8*)&sm.st.Bh[brow][bk] = bvh[i];
        *(bf16x8*)&sm.st.Bl[brow][bk] = bvl[i];
      }
    }
    __syncthreads();  // tile visible

    // ---- MFMA: A frag row = wave*16 + (lane&15), k = quad*8.. ----
    bf16x8 ah = *(const bf16x8*)&sm.st.Ah[wave * 16 + m][quad * 8];
    bf16x8 al = *(const bf16x8*)&sm.st.Al[wave * 16 + m][quad * 8];
#pragma unroll
    for (int nt = 0; nt < 13; ++nt) {
      bf16x8 bh = *(const bf16x8*)&sm.st.Bh[nt * 16 + m][quad * 8];
      bf16x8 bl = *(const bf16x8*)&sm.st.Bl[nt * 16 + m][quad * 8];
      acc[nt] = __builtin_amdgcn_mfma_f32_16x16x32_bf16(ah, bh, acc[nt], 0, 0, 0);
      acc[nt] = __builtin_amdgcn_mfma_f32_16x16x32_bf16(ah, bl, acc[nt], 0, 0, 0);
      acc[nt] = __builtin_amdgcn_mfma_f32_16x16x32_bf16(al, bh, acc[nt], 0, 0, 0);
    }
  }

  __syncthreads();  // staging LDS dead; reuse as z-buffer
  // C layout: col = lane&15, row = quad*4 + reg
#pragma unroll
  for (int nt = 0; nt < 13; ++nt)
#pragma unroll
    for (int r = 0; r < 4; ++r)
      sm.rd.z[wave * 16 + quad * 4 + r][nt * 16 + m] = acc[nt][r];
  __syncthreads();

  // phase 1: group maxes (64 rows x 20 groups of 10)
  for (int i = t; i < BM * Nd; i += 256) {
    int row = i / Nd, g = i % Nd;
    const float* zp = &sm.rd.z[row][g * Kd];
    float mx = zp[0];
#pragma unroll
    for (int j = 1; j < Kd; ++j) mx = fmaxf(mx, zp[j]);
    sm.rd.gmax[row][g] = mx;
  }
  __syncthreads();

  // phase 2: min over N, concat, argmax (+top-2 gap flag), write
  if (t < BM) {
    int row = t;
    float mn = sm.rd.gmax[row][0];
    float v1 = -3.4e38f, v2 = -3.4e38f;
    int best = 0;
    size_t orow = qrow0 + row;
    float* lp = out_logits + orow * (Nd + 1);
#pragma unroll
    for (int n = 0; n < Nd; ++n) {
      float v = sm.rd.gmax[row][n];
      lp[n] = v;
      mn = fminf(mn, v);
      if (v > v1) { v2 = v1; v1 = v; best = n; }  // first-occurrence argmax
      else v2 = fmaxf(v2, v);
    }
    lp[Nd] = mn - 1.0f;  // strictly below min, never the argmax
    out_pred[orow] = (float)best;
    if (v1 - v2 < TAU) {
      int idx = atomicAdd(flag_cnt, 1);
      if (idx < MAXF) flag_list[idx] = (int)orow;
    }
  }
}

// ---------------- fp64 exact refinement for near-tie rows ----------------
__global__ __launch_bounds__(256) void refine_pred(
    const float* __restrict__ query, const float* __restrict__ support,
    const float* __restrict__ gamma, const float* __restrict__ beta,
    const int* __restrict__ flag_cnt, const int* __restrict__ flag_list,
    float* __restrict__ out_pred) {
  __shared__ double A[Hd];     // qn_full * gamma
  __shared__ double red[16];
  __shared__ double zbuf[NKd];
  __shared__ double gmax[Nd];
  int cnt = *flag_cnt; if (cnt > MAXF) cnt = MAXF;
  if ((int)blockIdx.x >= cnt) return;
  int qrow = flag_list[blockIdx.x];
  int b = qrow / Qd;
  int t = threadIdx.x, lane = t & 63, w = t >> 6;
  const float* qx = query + (size_t)qrow * Hd;
  float xv[4];
  double sx = 0.0, sxx = 0.0;
#pragma unroll
  for (int i = 0; i < 4; ++i) {
    xv[i] = qx[t * 4 + i];
    sx += (double)xv[i]; sxx += (double)xv[i] * (double)xv[i];
  }
#pragma unroll
  for (int o = 32; o; o >>= 1) { sx += __shfl_xor(sx, o, 64); sxx += __shfl_xor(sxx, o, 64); }
  if (lane == 0) { red[w] = sx; red[8 + w] = sxx; }
  __syncthreads();
  double m = (red[0] + red[1] + red[2] + red[3]) * (1.0 / Hd);
  double var = (red[8] + red[9] + red[10] + red[11]) * (1.0 / Hd) - m * m;
  double r = 1.0 / sqrt(var + 1e-5);
  double s1 = 0.0, s2 = 0.0;
#pragma unroll
  for (int i = 0; i < 4; ++i) {
    int j = t * 4 + i;
    double g = (double)gamma[j], be = (double)beta[j];
    double qn = ((double)xv[i] - m) * r * g + be;
    double a = qn * g;
    A[j] = a; s1 += a; s2 += qn * be;
  }
#pragma unroll
  for (int o = 32; o; o >>= 1) { s1 += __shfl_xor(s1, o, 64); s2 += __shfl_xor(s2, o, 64); }
  __syncthreads();
  if (lane == 0) { red[w] = s1; red[8 + w] = s2; }
  __syncthreads();
  double S1 = red[0] + red[1] + red[2] + red[3];
  double S2 = red[8] + red[9] + red[10] + red[11];
  const float* sbase = support + (size_t)b * NKd * Hd;
  for (int row = w; row < NKd; row += 4) {
    const float* xr = sbase + (size_t)row * Hd;
    double tx = 0.0, txx = 0.0, tax = 0.0;
#pragma unroll
    for (int i = 0; i < 16; ++i) {
      int j = lane + i * 64;
      double x = (double)xr[j];
      tx += x; txx += x * x; tax += A[j] * x;
    }
#pragma unroll
    for (int o = 32; o; o >>= 1) {
      tx += __shfl_xor(tx, o, 64); txx += __shfl_xor(txx, o, 64); tax += __shfl_xor(tax, o, 64);
    }
    if (lane == 0) {
      double mm = tx * (1.0 / Hd);
      double vv = txx * (1.0 / Hd) - mm * mm;
      double rr = 1.0 / sqrt(vv + 1e-5);
      zbuf[row] = rr * (tax - mm * S1) + S2;
    }
  }
  __syncthreads();
  if (t < Nd) {
    double mx = zbuf[t * Kd];
#pragma unroll
    for (int j = 1; j < Kd; ++j) mx = fmax(mx, zbuf[t * Kd + j]);
    gmax[t] = mx;
  }
  __syncthreads();
  if (t == 0) {
    double bv = gmax[0]; int best = 0;
#pragma unroll
    for (int n = 1; n < Nd; ++n) if (gmax[n] > bv) { bv = gmax[n]; best = n; }
    out_pred[qrow] = (float)best;
  }
}

extern "C" void kernel_launch(void* const* d_in, const int* in_sizes, int n_in,
                              void* d_out, int out_size, void* d_ws, size_t ws_size,
                              hipStream_t stream) {
  const float* support = (const float*)d_in[0];
  const float* query   = (const float*)d_in[1];
  const float* gamma   = (const float*)d_in[2];
  const float* beta    = (const float*)d_in[3];

  float* out = (float*)d_out;
  float* out_logits = out;                                  // 32*2048*21
  float* out_pred   = out + (size_t)Bd * Qd * (Nd + 1);     // 32*2048

  const size_t plane = (size_t)Bd * NKd * Hd;               // 6.55M elems
  unsigned short* s_hi = (unsigned short*)d_ws;             // 13.1 MB
  unsigned short* s_lo = s_hi + plane;                      // 13.1 MB
  char* p = (char*)(s_lo + plane);
  float2* qstats = (float2*)p;                              // 512 KB
  p += (size_t)Bd * Qd * sizeof(float2);
  int* flag_cnt = (int*)p;
  int* flag_list = (int*)(p + 256);

  hipMemsetAsync(flag_cnt, 0, sizeof(int), stream);
  ln_support<<<(Bd * NKd + 3) / 4, 256, 0, stream>>>(support, gamma, beta, s_hi, s_lo, Bd * NKd);
  row_stats<<<(Bd * Qd + 3) / 4, 256, 0, stream>>>(query, qstats, Bd * Qd);
  gemm_reduce<<<dim3(Qd / BM, Bd), 256, 0, stream>>>(query, qstats, s_hi, s_lo, gamma, beta,
                                                     out_logits, out_pred, flag_cnt, flag_list);
  refine_pred<<<MAXF, 256, 0, stream>>>(query, support, gamma, beta, flag_cnt, flag_list, out_pred);
}